// Round 5
// baseline (183.341 us; speedup 1.0000x reference)
//
#include <hip/hip_runtime.h>
#include <hip/hip_bf16.h>

typedef short bf16x8 __attribute__((ext_vector_type(8)));
typedef float f32x4 __attribute__((ext_vector_type(4)));

#define MFMA16(a, b, c) __builtin_amdgcn_mfma_f32_16x16x32_bf16(a, b, c, 0, 0, 0)

static constexpr int SEQ = 1024;
static constexpr int DIM = 1024;
static constexpr int NH = 16;
static constexpr int HD = 64;

#if __has_builtin(__builtin_amdgcn_rcpf)
#define FAST_RCP(x) __builtin_amdgcn_rcpf(x)
#else
#define FAST_RCP(x) (1.0f / (x))
#endif

#if __has_builtin(__builtin_amdgcn_exp2f)
#define EXP2F(x) __builtin_amdgcn_exp2f(x)
#else
#define EXP2F(x) exp2f(x)
#endif

__device__ __forceinline__ int swz(int r) { return r ^ (r >> 3); } // row-XOR bank swizzle

// async global->LDS, 16B per lane. lds ptr must be wave-uniform (HW adds lane*16).
__device__ __forceinline__ void gload16(const __hip_bfloat16* g, __hip_bfloat16* l)
{
    typedef const __attribute__((address_space(1))) unsigned GU;
    typedef __attribute__((address_space(3))) unsigned LU;
    __builtin_amdgcn_global_load_lds((GU*)g, (LU*)l, 16, 0, 0);
}

// ---------------------------------------------------------------------------
// fused fp32->bf16 conversion for all 5 tensors (grid.y selects region)
// ---------------------------------------------------------------------------
__global__ __launch_bounds__(256) void cvt_all(
    const float* __restrict__ x,  const float* __restrict__ wq,
    const float* __restrict__ wk, const float* __restrict__ wv,
    const float* __restrict__ wo,
    __hip_bfloat16* __restrict__ xb,  __hip_bfloat16* __restrict__ wqb,
    __hip_bfloat16* __restrict__ wkb, __hip_bfloat16* __restrict__ wvb,
    __hip_bfloat16* __restrict__ wob)
{
    const int reg = blockIdx.y;
    const float* src; __hip_bfloat16* dst; int n;
    if      (reg == 0) { src = x;  dst = xb;  n = 2 * SEQ * DIM; }
    else if (reg == 1) { src = wq; dst = wqb; n = DIM * DIM; }
    else if (reg == 2) { src = wk; dst = wkb; n = DIM * DIM; }
    else if (reg == 3) { src = wv; dst = wvb; n = DIM * DIM; }
    else               { src = wo; dst = wob; n = DIM * DIM; }
    const int i = (blockIdx.x * 256 + threadIdx.x) * 4;
    if (i < n) {
        float4 v = *(const float4*)(src + i);
        __hip_bfloat16 t[4];
        t[0] = __float2bfloat16(v.x); t[1] = __float2bfloat16(v.y);
        t[2] = __float2bfloat16(v.z); t[3] = __float2bfloat16(v.w);
        *(ushort4*)(dst + i) = *(ushort4*)t;
    }
}

// ---------------------------------------------------------------------------
// GEMM 64x128 tile, BK=32, global_load_lds width-16 staging, 2-barrier loop.
// 768 blocks = 3/CU exact fit. QKV: grid.z selects W/bias/Y.
// ---------------------------------------------------------------------------
__global__ __launch_bounds__(256) void gemm_qkv(
    const __hip_bfloat16* __restrict__ A,
    const __hip_bfloat16* __restrict__ W0, const __hip_bfloat16* __restrict__ W1,
    const __hip_bfloat16* __restrict__ W2,
    const float* __restrict__ b0, const float* __restrict__ b1,
    const float* __restrict__ b2,
    __hip_bfloat16* __restrict__ Y0, __hip_bfloat16* __restrict__ Y1,
    __hip_bfloat16* __restrict__ Y2,
    int M, int N, int K)
{
    __shared__ __align__(16) __hip_bfloat16 As[64 * 32];    // 4 KB: one issue
    __shared__ __align__(16) __hip_bfloat16 Ws[128 * 32];   // 8 KB: two issues

    const int z = blockIdx.z;
    const __hip_bfloat16* W = (z == 0) ? W0 : ((z == 1) ? W1 : W2);
    const float* bias = (z == 0) ? b0 : ((z == 1) ? b1 : b2);
    __hip_bfloat16* Y = (z == 0) ? Y0 : ((z == 1) ? Y1 : Y2);

    const int tid = threadIdx.x;
    const int wv = tid >> 6, lane = tid & 63;
    const int col16 = lane & 15, quad = lane >> 4;
    const int m0 = blockIdx.x * 64, n0 = blockIdx.y * 128;

    const __hip_bfloat16* ga = A + (size_t)(m0 + (tid >> 2)) * K + (tid & 3) * 8;
    const __hip_bfloat16* gb = W + (size_t)(n0 + (tid >> 2)) * K + (tid & 3) * 8;
    __hip_bfloat16* lA = As + wv * 512;          // wave-uniform base (1 KB/wave)
    __hip_bfloat16* lB = Ws + wv * 512;

    const int wr = wv >> 1, wc = wv & 1;
    const __hip_bfloat16* ar = As + (wr * 32 + col16) * 32 + quad * 8;
    const __hip_bfloat16* br = Ws + (wc * 64 + col16) * 32 + quad * 8;

    f32x4 acc[8] = {};

    for (int k0 = 0; k0 < K; k0 += 32) {
        gload16(ga + k0,                  lA);
        gload16(gb + k0,                  lB);
        gload16(gb + k0 + (size_t)64 * K, lB + 2048);
        __syncthreads();   // drains vmcnt -> LDS tile valid
        bf16x8 af[2], bfm[4];
#pragma unroll
        for (int mt = 0; mt < 2; ++mt) af[mt] = *(const bf16x8*)(ar + mt * 16 * 32);
#pragma unroll
        for (int nt = 0; nt < 4; ++nt) bfm[nt] = *(const bf16x8*)(br + nt * 16 * 32);
#pragma unroll
        for (int mt = 0; mt < 2; ++mt)
#pragma unroll
            for (int nt = 0; nt < 4; ++nt)
                acc[mt * 4 + nt] = MFMA16(af[mt], bfm[nt], acc[mt * 4 + nt]);
        __syncthreads();   // reads done before next tile overwrites
    }

#pragma unroll
    for (int nt = 0; nt < 4; ++nt) {
        const int n = n0 + wc * 64 + nt * 16 + col16;
        const float bv = bias[n];
#pragma unroll
        for (int mt = 0; mt < 2; ++mt) {
#pragma unroll
            for (int r = 0; r < 4; ++r) {
                const int m = m0 + wr * 32 + mt * 16 + quad * 4 + r;
                Y[(size_t)m * N + n] = __float2bfloat16(acc[mt * 4 + nt][r] + bv);
            }
        }
    }
}

// ---------------------------------------------------------------------------
// O-proj split-K=2, same gload_lds structure. Partial 0 carries bias.
// ---------------------------------------------------------------------------
__global__ __launch_bounds__(256) void gemm_osplit(
    const __hip_bfloat16* __restrict__ A,
    const __hip_bfloat16* __restrict__ W,
    const float* __restrict__ bias,
    float* __restrict__ Y0, float* __restrict__ Y1,
    int M, int N, int K)
{
    __shared__ __align__(16) __hip_bfloat16 As[64 * 32];
    __shared__ __align__(16) __hip_bfloat16 Ws[128 * 32];

    const int z = blockIdx.z;
    float* Y = (z == 0) ? Y0 : Y1;
    const int kb = z * 512;

    const int tid = threadIdx.x;
    const int wv = tid >> 6, lane = tid & 63;
    const int col16 = lane & 15, quad = lane >> 4;
    const int m0 = blockIdx.x * 64, n0 = blockIdx.y * 128;

    const __hip_bfloat16* ga = A + (size_t)(m0 + (tid >> 2)) * K + (tid & 3) * 8 + kb;
    const __hip_bfloat16* gb = W + (size_t)(n0 + (tid >> 2)) * K + (tid & 3) * 8 + kb;
    __hip_bfloat16* lA = As + wv * 512;
    __hip_bfloat16* lB = Ws + wv * 512;

    const int wr = wv >> 1, wc = wv & 1;
    const __hip_bfloat16* ar = As + (wr * 32 + col16) * 32 + quad * 8;
    const __hip_bfloat16* br = Ws + (wc * 64 + col16) * 32 + quad * 8;

    f32x4 acc[8] = {};

    for (int k0 = 0; k0 < 512; k0 += 32) {
        gload16(ga + k0,                  lA);
        gload16(gb + k0,                  lB);
        gload16(gb + k0 + (size_t)64 * K, lB + 2048);
        __syncthreads();
        bf16x8 af[2], bfm[4];
#pragma unroll
        for (int mt = 0; mt < 2; ++mt) af[mt] = *(const bf16x8*)(ar + mt * 16 * 32);
#pragma unroll
        for (int nt = 0; nt < 4; ++nt) bfm[nt] = *(const bf16x8*)(br + nt * 16 * 32);
#pragma unroll
        for (int mt = 0; mt < 2; ++mt)
#pragma unroll
            for (int nt = 0; nt < 4; ++nt)
                acc[mt * 4 + nt] = MFMA16(af[mt], bfm[nt], acc[mt * 4 + nt]);
        __syncthreads();
    }

#pragma unroll
    for (int nt = 0; nt < 4; ++nt) {
        const int n = n0 + wc * 64 + nt * 16 + col16;
        const float bv = (z == 0) ? bias[n] : 0.0f;
#pragma unroll
        for (int mt = 0; mt < 2; ++mt) {
#pragma unroll
            for (int r = 0; r < 4; ++r) {
                const int m = m0 + wr * 32 + mt * 16 + quad * 4 + r;
                Y[(size_t)m * N + n] = acc[mt * 4 + nt][r] + bv;
            }
        }
    }
}

// ---------------------------------------------------------------------------
// Attention — R2 structure, now with optional j-split across blockIdx.z
// (nz=2: each block handles 512 js, 4 iters/half, writes f32 partials;
//  nz=1: legacy full path writing AO directly). Occupancy: 1024 blocks
// (4/CU grid-capped) -> 2048 blocks (6/CU LDS-capped, 24 waves/CU).
// ---------------------------------------------------------------------------
__global__ __launch_bounds__(256) void attn_kernel(
    const __hip_bfloat16* __restrict__ Q,
    const __hip_bfloat16* __restrict__ K,
    const __hip_bfloat16* __restrict__ V,
    const float* __restrict__ alpha, const float* __restrict__ phi,
    const float* __restrict__ temperature,
    float* __restrict__ Op0, float* __restrict__ Op1,
    float* __restrict__ Dp0, float* __restrict__ Dp1,
    __hip_bfloat16* __restrict__ AO, int nz)
{
    __shared__ __align__(16) char smem[18432 + 5120];
    __hip_bfloat16* VtBase = (__hip_bfloat16*)smem;
    __hip_bfloat16* PlBase = (__hip_bfloat16*)(smem + 18432);
    float* Ocomb = (float*)smem;                 // [2][16][68]
    float* Dl    = (float*)(smem + 2 * 16 * 68 * 4);

    const int tid = threadIdx.x;
    const int wv = tid >> 6, lane = tid & 63;
    const int col16 = lane & 15, quad = lane >> 4;
    const int g = wv & 1, half = wv >> 1;

    const int bh = blockIdx.y, b = bh >> 4, h = bh & 15;
    const int i0 = blockIdx.x * 32 + g * 16;
    const size_t base = ((size_t)b * SEQ) * DIM + (size_t)h * HD;

    const int z = blockIdx.z;
    const int jb = z * (SEQ / nz);            // this block's j-range start
    const int hrange = SEQ / nz / 2;          // js per wave-half
    const int niter = hrange >> 6;            // 64-j tiles per half

    const float tempv = fabsf(temperature[0]) + 0.1f;
    const float simscale = 1.0f / (8.0f * tempv);
    const float freqs[5] = {31.0f, 37.0f, 41.0f, 43.0f, 47.0f};

    // degree-7 poly of log2e*score(s); w = rcp(1+exp2(-poly(s)))  [R5-validated]
    float p[8] = {0.f, 0.f, 0.f, 0.f, 0.f, 0.f, 0.f, 0.f};
#pragma unroll
    for (int f = 0; f < 5; ++f) {
        const float a  = alpha[h * 5 + f] * 1.44269504089f;  // fold log2(e)
        const float ph = phi[h * 5 + f];
        const float sp = __sinf(ph), cp = __cosf(ph);
        const float c  = 6.28318530718f * simscale / freqs[f];
        const float c2 = c * c, c3 = c2 * c, c4 = c2 * c2;
        const float c5 = c4 * c, c6 = c4 * c2, c7 = c4 * c3;
        p[0] += a * sp;
        p[1] += a * cp * c;
        p[2] -= a * sp * c2 * 0.5f;
        p[3] -= a * cp * c3 * (1.0f / 6.0f);
        p[4] += a * sp * c4 * (1.0f / 24.0f);
        p[5] += a * cp * c5 * (1.0f / 120.0f);
        p[6] -= a * sp * c6 * (1.0f / 720.0f);
        p[7] -= a * cp * c7 * (1.0f / 5040.0f);
    }

    const __hip_bfloat16* qrow = Q + base + (size_t)(i0 + col16) * DIM + quad * 8;
    const bf16x8 qa0 = *(const bf16x8*)(qrow);
    const bf16x8 qa1 = *(const bf16x8*)(qrow + 32);

    const __hip_bfloat16* kbase = K + base + (size_t)col16 * DIM + quad * 8;

    const int tl = tid & 127;
    const int sc0 = (tl & 7) * 8;
    const int sx  = tl & 7;
    const int jj0 = (tl >> 3) * 2;
    __hip_bfloat16* VtH = VtBase + half * 64 * 72;
    __hip_bfloat16* rowp[8];
#pragma unroll
    for (int e = 0; e < 8; ++e) rowp[e] = VtH + (sc0 + (e ^ sx)) * 72;

    const __hip_bfloat16* vrd[4];
#pragma unroll
    for (int t = 0; t < 4; ++t)
        vrd[t] = VtH + swz(t * 16 + col16) * 72 + quad * 8;

    __hip_bfloat16* PlW = PlBase + wv * 16 * 40;
    const __hip_bfloat16* plr = PlW + swz(col16) * 40 + quad * 8;
    __hip_bfloat16* plw[4];
#pragma unroll
    for (int r = 0; r < 4; ++r) plw[r] = PlW + swz(quad * 4 + r) * 40;

    f32x4 o[4] = {};
    float denom[4] = {0.f, 0.f, 0.f, 0.f};

    bf16x8 vr[2][2];   // prefetched V regs
    bf16x8 kf[4][2];   // prefetched K frags

    {
        const int j0 = jb + half * hrange;
#pragma unroll
        for (int s = 0; s < 2; ++s) {
            const __hip_bfloat16* vp = V + base + (size_t)(j0 + jj0 + 32 * s) * DIM + sc0;
            vr[s][0] = *(const bf16x8*)(vp);
            vr[s][1] = *(const bf16x8*)(vp + DIM);
        }
#pragma unroll
        for (int u = 0; u < 4; ++u) {
            const __hip_bfloat16* kp = kbase + (size_t)(j0 + u * 16) * DIM;
            kf[u][0] = *(const bf16x8*)(kp);
            kf[u][1] = *(const bf16x8*)(kp + 32);
        }
    }

    for (int it = 0; it < niter; ++it) {
        __syncthreads();
#pragma unroll
        for (int s = 0; s < 2; ++s) {
#pragma unroll
            for (int e = 0; e < 8; ++e) {
                unsigned pk = ((unsigned)(unsigned short)vr[s][0][e]) |
                              (((unsigned)(unsigned short)vr[s][1][e]) << 16);
                *(unsigned*)(rowp[e] + jj0 + 32 * s) = pk;
            }
        }
        __syncthreads();

        const int j1 = jb + half * hrange + (it + 1) * 64;
        if (it + 1 < niter) {
#pragma unroll
            for (int s = 0; s < 2; ++s) {
                const __hip_bfloat16* vp = V + base + (size_t)(j1 + jj0 + 32 * s) * DIM + sc0;
                vr[s][0] = *(const bf16x8*)(vp);
                vr[s][1] = *(const bf16x8*)(vp + DIM);
            }
        }

        f32x4 sa4[4];
#pragma unroll
        for (int u = 0; u < 4; ++u) {
            f32x4 zz = {};
            zz = MFMA16(qa0, kf[u][0], zz);
            zz = MFMA16(qa1, kf[u][1], zz);
            sa4[u] = zz;
        }

        if (it + 1 < niter) {
#pragma unroll
            for (int u = 0; u < 4; ++u) {
                const __hip_bfloat16* kp = kbase + (size_t)(j1 + u * 16) * DIM;
                kf[u][0] = *(const bf16x8*)(kp);
                kf[u][1] = *(const bf16x8*)(kp + 32);
            }
        }

#pragma unroll
        for (int sub = 0; sub < 2; ++sub) {
#pragma unroll
            for (int s2 = 0; s2 < 2; ++s2) {
                const int u = sub * 2 + s2;
#pragma unroll
                for (int r = 0; r < 4; ++r) {
                    const float sv = sa4[u][r];
                    float sc = fmaf(sv, p[7], p[6]);
                    sc = fmaf(sv, sc, p[5]);
                    sc = fmaf(sv, sc, p[4]);
                    sc = fmaf(sv, sc, p[3]);
                    sc = fmaf(sv, sc, p[2]);
                    sc = fmaf(sv, sc, p[1]);
                    sc = fmaf(sv, sc, p[0]);
                    const float w = FAST_RCP(1.0f + EXP2F(-sc));
                    denom[r] += w;
                    plw[r][s2 * 16 + col16] = __float2bfloat16(w);
                }
            }
            bf16x8 pa = *(const bf16x8*)plr;
#pragma unroll
            for (int t = 0; t < 4; ++t) {
                bf16x8 vb = *(const bf16x8*)(vrd[t] + 32 * sub);
                o[t] = MFMA16(pa, vb, o[t]);
            }
        }
    }

#pragma unroll
    for (int r = 0; r < 4; ++r) {
        float d = denom[r];
        d += __shfl_xor(d, 1);
        d += __shfl_xor(d, 2);
        d += __shfl_xor(d, 4);
        d += __shfl_xor(d, 8);
        denom[r] = d;
    }

    __syncthreads();
    if (half == 1) {
#pragma unroll
        for (int t = 0; t < 4; ++t)
#pragma unroll
            for (int r = 0; r < 4; ++r)
                Ocomb[(g * 16 + quad * 4 + r) * 68 + t * 16 + col16] = o[t][r];
        if (col16 == 0) {
#pragma unroll
            for (int r = 0; r < 4; ++r) Dl[g * 16 + quad * 4 + r] = denom[r];
        }
    }
    __syncthreads();
    if (half == 0) {
        if (nz == 1) {
            // legacy direct path: divide and write bf16 AO
#pragma unroll
            for (int r = 0; r < 4; ++r)
                denom[r] = denom[r] + Dl[g * 16 + quad * 4 + r] + 1e-10f;
#pragma unroll
            for (int t = 0; t < 4; ++t) {
#pragma unroll
                for (int r = 0; r < 4; ++r) {
                    const float val =
                        (o[t][r] + Ocomb[(g * 16 + quad * 4 + r) * 68 + t * 16 + col16]) / denom[r];
                    const size_t row = (size_t)b * SEQ + i0 + quad * 4 + r;
                    AO[row * DIM + h * HD + t * 16 + col16] = __float2bfloat16(val);
                }
            }
        } else {
            // partial path: f32 partial O (pre-division) + partial denominator
            float* Op = (z == 0) ? Op0 : Op1;
            float* Dp = (z == 0) ? Dp0 : Dp1;
#pragma unroll
            for (int r = 0; r < 4; ++r)
                denom[r] = denom[r] + Dl[g * 16 + quad * 4 + r];
            if (col16 == 0) {
#pragma unroll
                for (int r = 0; r < 4; ++r)
                    Dp[(size_t)bh * SEQ + i0 + quad * 4 + r] = denom[r];
            }
#pragma unroll
            for (int t = 0; t < 4; ++t) {
#pragma unroll
                for (int r = 0; r < 4; ++r) {
                    const size_t prow = (size_t)bh * SEQ + i0 + quad * 4 + r;
                    Op[prow * 64 + t * 16 + col16] =
                        o[t][r] + Ocomb[(g * 16 + quad * 4 + r) * 68 + t * 16 + col16];
                }
            }
        }
    }
}

// ---------------------------------------------------------------------------
// Combine the two j-split partials: AO = (O0+O1)/(D0+D1+1e-10), bf16.
// One block per (b,i) row; thread t -> head h=t>>4, d-quad (t&15)*4.
// ---------------------------------------------------------------------------
__global__ __launch_bounds__(256) void attn_combine(
    const float* __restrict__ O0, const float* __restrict__ O1,
    const float* __restrict__ D0, const float* __restrict__ D1,
    __hip_bfloat16* __restrict__ AO)
{
    const int row = blockIdx.x;               // b*SEQ + i
    const int b = row >> 10, i = row & 1023;
    const int t = threadIdx.x;
    const int h = t >> 4, dq = (t & 15) * 4;
    const int bh = b * 16 + h;
    const size_t prow = (size_t)bh * SEQ + i;
    const size_t obase = prow * 64 + dq;

    const float4 a0 = *(const float4*)(O0 + obase);
    const float4 a1 = *(const float4*)(O1 + obase);
    const float dn = D0[prow] + D1[prow] + 1e-10f;
    const float rdn = 1.0f / dn;

    __hip_bfloat16 tv[4];
    tv[0] = __float2bfloat16((a0.x + a1.x) * rdn);
    tv[1] = __float2bfloat16((a0.y + a1.y) * rdn);
    tv[2] = __float2bfloat16((a0.z + a1.z) * rdn);
    tv[3] = __float2bfloat16((a0.w + a1.w) * rdn);
    *(ushort4*)(AO + (size_t)row * DIM + h * HD + dq) = *(ushort4*)tv;
}

// ---------------------------------------------------------------------------
// LayerNorm over last dim (1024), sums the two split-K partials of O-proj.
// ---------------------------------------------------------------------------
__global__ __launch_bounds__(256) void ln_kernel(
    const float* __restrict__ Yp0,
    const float* __restrict__ Yp1,
    const float* __restrict__ gamma,
    const float* __restrict__ beta,
    float* __restrict__ out)
{
    const int row = blockIdx.x;
    const float* y0 = Yp0 + (size_t)row * DIM;
    const float* y1 = Yp1 + (size_t)row * DIM;

    float v[4];
    float s = 0.f, s2 = 0.f;
#pragma unroll
    for (int e = 0; e < 4; ++e) {
        const int idx = threadIdx.x + e * 256;
        v[e] = y0[idx] + y1[idx];
        s += v[e];
        s2 += v[e] * v[e];
    }
#pragma unroll
    for (int off = 1; off < 64; off <<= 1) {
        s  += __shfl_xor(s, off);
        s2 += __shfl_xor(s2, off);
    }
    __shared__ float ps[4], ps2[4];
    const int wave = threadIdx.x >> 6;
    if ((threadIdx.x & 63) == 0) { ps[wave] = s; ps2[wave] = s2; }
    __syncthreads();
    s  = ps[0] + ps[1] + ps[2] + ps[3];
    s2 = ps2[0] + ps2[1] + ps2[2] + ps2[3];

    const float mu   = s * (1.0f / DIM);
    const float var  = s2 * (1.0f / DIM) - mu * mu;
    const float rstd = rsqrtf(var + 1e-5f);

#pragma unroll
    for (int e = 0; e < 4; ++e) {
        const int idx = threadIdx.x + e * 256;
        out[(size_t)row * DIM + idx] =
            (v[e] - mu) * rstd * gamma[idx] + beta[idx];
    }
}

// ---------------------------------------------------------------------------
extern "C" void kernel_launch(void* const* d_in, const int* in_sizes, int n_in,
                              void* d_out, int out_size, void* d_ws, size_t ws_size,
                              hipStream_t stream)
{
    const float* x     = (const float*)d_in[0];
    const float* Wq    = (const float*)d_in[1];
    const float* bq    = (const float*)d_in[2];
    const float* Wk    = (const float*)d_in[3];
    const float* bk    = (const float*)d_in[4];
    const float* Wv    = (const float*)d_in[5];
    const float* bv    = (const float*)d_in[6];
    const float* Wo    = (const float*)d_in[7];
    const float* bo    = (const float*)d_in[8];
    const float* alpha = (const float*)d_in[9];
    const float* phi   = (const float*)d_in[10];
    const float* temp  = (const float*)d_in[11];
    const float* gamma = (const float*)d_in[12];
    const float* beta  = (const float*)d_in[13];

    float* out = (float*)d_out;

    const int B = 2;
    const int M = B * SEQ;                 // 2048

    // ws layout (MB):
    //   [0,4)   xb    [4,6) Wqb   [6,8) Wkb   [8,10) Wvb   [10,12) Wob
    //   [12,16) Qb    [16,20) Kb  [20,24) Vb  [24,28) AO
    //   Yp0 (fp32 8MB) aliases [0,8)  — xb/Wqb/Wkb dead by O-proj
    //   Yp1 (fp32 8MB) aliases [12,20) — Qb/Kb dead by O-proj
    //   attn j-split partials (live only between attn and combine):
    //     Op0 aliases [0,8) (xb/Wqb/Wkb dead at attn time)
    //     Dp0/Dp1 alias [8,8.25) (Wvb dead at attn time)
    //     Op1 at [28,36) — REQUIRES ws >= 36MB, else legacy nz=1 path
    char* wsb = (char*)d_ws;
    __hip_bfloat16* xb  = (__hip_bfloat16*)(wsb + 0);
    __hip_bfloat16* Wqb = (__hip_bfloat16*)(wsb + (4u  << 20));
    __hip_bfloat16* Wkb = (__hip_bfloat16*)(wsb + (6u  << 20));
    __hip_bfloat16* Wvb = (__hip_bfloat16*)(wsb + (8u  << 20));
    __hip_bfloat16* Wob = (__hip_bfloat16*)(wsb + (10u << 20));
    __hip_bfloat16* Qb  = (__hip_bfloat16*)(wsb + (12u << 20));
    __hip_bfloat16* Kb  = (__hip_bfloat16*)(wsb + (16u << 20));
    __hip_bfloat16* Vb  = (__hip_bfloat16*)(wsb + (20u << 20));
    __hip_bfloat16* AO  = (__hip_bfloat16*)(wsb + (24u << 20));
    float*          Yp0 = (float*)(wsb + 0);
    float*          Yp1 = (float*)(wsb + (12u << 20));
    float*          Op0 = (float*)(wsb + 0);
    float*          Dp0 = (float*)(wsb + (8u << 20));
    float*          Dp1 = (float*)(wsb + (8u << 20) + (1u << 18));
    float*          Op1 = (float*)(wsb + (28u << 20));

    const bool wide = ws_size >= (36u << 20);

    hipLaunchKernelGGL(cvt_all, dim3(2048, 5), dim3(256), 0, stream,
                       x, Wq, Wk, Wv, Wo, xb, Wqb, Wkb, Wvb, Wob);

    hipLaunchKernelGGL(gemm_qkv, dim3(M / 64, DIM / 128, 3), dim3(256), 0, stream,
                       xb, Wqb, Wkb, Wvb, bq, bk, bv, Qb, Kb, Vb, M, DIM, DIM);

    if (wide) {
        hipLaunchKernelGGL(attn_kernel, dim3(SEQ / 32, B * NH, 2), dim3(256), 0, stream,
                           Qb, Kb, Vb, alpha, phi, temp, Op0, Op1, Dp0, Dp1, AO, 2);
        hipLaunchKernelGGL(attn_combine, dim3(M), dim3(256), 0, stream,
                           Op0, Op1, Dp0, Dp1, AO);
    } else {
        hipLaunchKernelGGL(attn_kernel, dim3(SEQ / 32, B * NH, 1), dim3(256), 0, stream,
                           Qb, Kb, Vb, alpha, phi, temp, Op0, Op1, Dp0, Dp1, AO, 1);
    }

    hipLaunchKernelGGL(gemm_osplit, dim3(M / 64, DIM / 128, 2), dim3(256), 0, stream,
                       AO, Wob, bo, Yp0, Yp1, M, DIM, DIM);

    hipLaunchKernelGGL(ln_kernel, dim3(M), dim3(256), 0, stream,
                       Yp0, Yp1, gamma, beta, out);
}

// Round 6
// 171.218 us; speedup vs baseline: 1.0708x; 1.0708x over previous
//
#include <hip/hip_runtime.h>
#include <hip/hip_bf16.h>

typedef short bf16x8 __attribute__((ext_vector_type(8)));
typedef float f32x4 __attribute__((ext_vector_type(4)));

#define MFMA16(a, b, c) __builtin_amdgcn_mfma_f32_16x16x32_bf16(a, b, c, 0, 0, 0)

static constexpr int SEQ = 1024;
static constexpr int DIM = 1024;
static constexpr int NH = 16;
static constexpr int HD = 64;

#if __has_builtin(__builtin_amdgcn_rcpf)
#define FAST_RCP(x) __builtin_amdgcn_rcpf(x)
#else
#define FAST_RCP(x) (1.0f / (x))
#endif

#if __has_builtin(__builtin_amdgcn_exp2f)
#define EXP2F(x) __builtin_amdgcn_exp2f(x)
#else
#define EXP2F(x) exp2f(x)
#endif

__device__ __forceinline__ int swz(int r) { return r ^ (r >> 3); } // row-XOR bank swizzle

// async global->LDS, 16B per lane. lds ptr must be wave-uniform (HW adds lane*16).
__device__ __forceinline__ void gload16(const __hip_bfloat16* g, __hip_bfloat16* l)
{
    typedef const __attribute__((address_space(1))) unsigned GU;
    typedef __attribute__((address_space(3))) unsigned LU;
    __builtin_amdgcn_global_load_lds((GU*)g, (LU*)l, 16, 0, 0);
}

// ---------------------------------------------------------------------------
// fused fp32->bf16 conversion for all 5 tensors (grid.y selects region)
// ---------------------------------------------------------------------------
__global__ __launch_bounds__(256) void cvt_all(
    const float* __restrict__ x,  const float* __restrict__ wq,
    const float* __restrict__ wk, const float* __restrict__ wv,
    const float* __restrict__ wo,
    __hip_bfloat16* __restrict__ xb,  __hip_bfloat16* __restrict__ wqb,
    __hip_bfloat16* __restrict__ wkb, __hip_bfloat16* __restrict__ wvb,
    __hip_bfloat16* __restrict__ wob)
{
    const int reg = blockIdx.y;
    const float* src; __hip_bfloat16* dst; int n;
    if      (reg == 0) { src = x;  dst = xb;  n = 2 * SEQ * DIM; }
    else if (reg == 1) { src = wq; dst = wqb; n = DIM * DIM; }
    else if (reg == 2) { src = wk; dst = wkb; n = DIM * DIM; }
    else if (reg == 3) { src = wv; dst = wvb; n = DIM * DIM; }
    else               { src = wo; dst = wob; n = DIM * DIM; }
    const int i = (blockIdx.x * 256 + threadIdx.x) * 4;
    if (i < n) {
        float4 v = *(const float4*)(src + i);
        __hip_bfloat16 t[4];
        t[0] = __float2bfloat16(v.x); t[1] = __float2bfloat16(v.y);
        t[2] = __float2bfloat16(v.z); t[3] = __float2bfloat16(v.w);
        *(ushort4*)(dst + i) = *(ushort4*)t;
    }
}

// ---------------------------------------------------------------------------
// GEMM 64x128 tile, BK=64 (half the barriers of BK=32), gload_lds staging
// with BOTH-SIDES XOR swizzle (rule #21): LDS dest linear, global source
// column pre-swizzled (slot^row&7), read slot XOR'd the same way ->
// conflict-free ds_read_b128 from the 128B-row tile. 768 blocks = 3/CU.
// ---------------------------------------------------------------------------
__global__ __launch_bounds__(256) void gemm_qkv(
    const __hip_bfloat16* __restrict__ A,
    const __hip_bfloat16* __restrict__ W0, const __hip_bfloat16* __restrict__ W1,
    const __hip_bfloat16* __restrict__ W2,
    const float* __restrict__ b0, const float* __restrict__ b1,
    const float* __restrict__ b2,
    __hip_bfloat16* __restrict__ Y0, __hip_bfloat16* __restrict__ Y1,
    __hip_bfloat16* __restrict__ Y2,
    int M, int N, int K)
{
    __shared__ __align__(16) __hip_bfloat16 As[64 * 64];    // 8 KB:  2 issues
    __shared__ __align__(16) __hip_bfloat16 Ws[128 * 64];   // 16 KB: 4 issues

    const int z = blockIdx.z;
    const __hip_bfloat16* W = (z == 0) ? W0 : ((z == 1) ? W1 : W2);
    const float* bias = (z == 0) ? b0 : ((z == 1) ? b1 : b2);
    __hip_bfloat16* Y = (z == 0) ? Y0 : ((z == 1) ? Y1 : Y2);

    const int tid = threadIdx.x;
    const int wv = tid >> 6, lane = tid & 63;
    const int col16 = lane & 15, quad = lane >> 4;
    const int m0 = blockIdx.x * 64, n0 = blockIdx.y * 128;
    const int wr = wv >> 1, wc = wv & 1;

    // staging: thread t -> row t>>3, col-slot (t&7)^((t>>3)&7) (pre-swizzled src)
    const int scol = ((tid & 7) ^ ((tid >> 3) & 7)) * 8;
    const __hip_bfloat16* ga = A + (size_t)(m0 + (tid >> 3)) * K + scol;
    const __hip_bfloat16* gb = W + (size_t)(n0 + (tid >> 3)) * K + scol;
    __hip_bfloat16* lA = As + wv * 512;          // wave-uniform base
    __hip_bfloat16* lB = Ws + wv * 512;

    // fragment reads: row = base + col16 (row&7 == col16&7 for all mt/nt),
    // slot' = (quad + kh*4) ^ (col16&7)
    const int c7 = col16 & 7;
    const int so0 = ((quad)     ^ c7) * 8;
    const int so1 = ((quad + 4) ^ c7) * 8;
    const __hip_bfloat16* ar = As + (wr * 32 + col16) * 64;
    const __hip_bfloat16* br = Ws + (wc * 64 + col16) * 64;

    f32x4 acc[8] = {};

    for (int k0 = 0; k0 < K; k0 += 64) {
        gload16(ga + k0,                  lA);
        gload16(ga + k0 + (size_t)32 * K, lA + 2048);
        gload16(gb + k0,                  lB);
        gload16(gb + k0 + (size_t)32 * K, lB + 2048);
        gload16(gb + k0 + (size_t)64 * K, lB + 4096);
        gload16(gb + k0 + (size_t)96 * K, lB + 6144);
        __syncthreads();   // drains vmcnt -> LDS tile valid
#pragma unroll
        for (int kh = 0; kh < 2; ++kh) {
            const int so = (kh == 0) ? so0 : so1;
            bf16x8 af[2], bfm[4];
#pragma unroll
            for (int mt = 0; mt < 2; ++mt) af[mt] = *(const bf16x8*)(ar + mt * 16 * 64 + so);
#pragma unroll
            for (int nt = 0; nt < 4; ++nt) bfm[nt] = *(const bf16x8*)(br + nt * 16 * 64 + so);
#pragma unroll
            for (int mt = 0; mt < 2; ++mt)
#pragma unroll
                for (int nt = 0; nt < 4; ++nt)
                    acc[mt * 4 + nt] = MFMA16(af[mt], bfm[nt], acc[mt * 4 + nt]);
        }
        __syncthreads();   // reads done before next tile overwrites
    }

#pragma unroll
    for (int nt = 0; nt < 4; ++nt) {
        const int n = n0 + wc * 64 + nt * 16 + col16;
        const float bv = bias[n];
#pragma unroll
        for (int mt = 0; mt < 2; ++mt) {
#pragma unroll
            for (int r = 0; r < 4; ++r) {
                const int m = m0 + wr * 32 + mt * 16 + quad * 4 + r;
                Y[(size_t)m * N + n] = __float2bfloat16(acc[mt * 4 + nt][r] + bv);
            }
        }
    }
}

// ---------------------------------------------------------------------------
// O-proj split-K=2, same BK=64 swizzled structure. Partial 0 carries bias.
// ---------------------------------------------------------------------------
__global__ __launch_bounds__(256) void gemm_osplit(
    const __hip_bfloat16* __restrict__ A,
    const __hip_bfloat16* __restrict__ W,
    const float* __restrict__ bias,
    float* __restrict__ Y0, float* __restrict__ Y1,
    int M, int N, int K)
{
    __shared__ __align__(16) __hip_bfloat16 As[64 * 64];
    __shared__ __align__(16) __hip_bfloat16 Ws[128 * 64];

    const int z = blockIdx.z;
    float* Y = (z == 0) ? Y0 : Y1;
    const int kb = z * 512;

    const int tid = threadIdx.x;
    const int wv = tid >> 6, lane = tid & 63;
    const int col16 = lane & 15, quad = lane >> 4;
    const int m0 = blockIdx.x * 64, n0 = blockIdx.y * 128;
    const int wr = wv >> 1, wc = wv & 1;

    const int scol = ((tid & 7) ^ ((tid >> 3) & 7)) * 8;
    const __hip_bfloat16* ga = A + (size_t)(m0 + (tid >> 3)) * K + scol + kb;
    const __hip_bfloat16* gb = W + (size_t)(n0 + (tid >> 3)) * K + scol + kb;
    __hip_bfloat16* lA = As + wv * 512;
    __hip_bfloat16* lB = Ws + wv * 512;

    const int c7 = col16 & 7;
    const int so0 = ((quad)     ^ c7) * 8;
    const int so1 = ((quad + 4) ^ c7) * 8;
    const __hip_bfloat16* ar = As + (wr * 32 + col16) * 64;
    const __hip_bfloat16* br = Ws + (wc * 64 + col16) * 64;

    f32x4 acc[8] = {};

    for (int k0 = 0; k0 < 512; k0 += 64) {
        gload16(ga + k0,                  lA);
        gload16(ga + k0 + (size_t)32 * K, lA + 2048);
        gload16(gb + k0,                  lB);
        gload16(gb + k0 + (size_t)32 * K, lB + 2048);
        gload16(gb + k0 + (size_t)64 * K, lB + 4096);
        gload16(gb + k0 + (size_t)96 * K, lB + 6144);
        __syncthreads();
#pragma unroll
        for (int kh = 0; kh < 2; ++kh) {
            const int so = (kh == 0) ? so0 : so1;
            bf16x8 af[2], bfm[4];
#pragma unroll
            for (int mt = 0; mt < 2; ++mt) af[mt] = *(const bf16x8*)(ar + mt * 16 * 64 + so);
#pragma unroll
            for (int nt = 0; nt < 4; ++nt) bfm[nt] = *(const bf16x8*)(br + nt * 16 * 64 + so);
#pragma unroll
            for (int mt = 0; mt < 2; ++mt)
#pragma unroll
                for (int nt = 0; nt < 4; ++nt)
                    acc[mt * 4 + nt] = MFMA16(af[mt], bfm[nt], acc[mt * 4 + nt]);
        }
        __syncthreads();
    }

#pragma unroll
    for (int nt = 0; nt < 4; ++nt) {
        const int n = n0 + wc * 64 + nt * 16 + col16;
        const float bv = (z == 0) ? bias[n] : 0.0f;
#pragma unroll
        for (int mt = 0; mt < 2; ++mt) {
#pragma unroll
            for (int r = 0; r < 4; ++r) {
                const int m = m0 + wr * 32 + mt * 16 + quad * 4 + r;
                Y[(size_t)m * N + n] = acc[mt * 4 + nt][r] + bv;
            }
        }
    }
}

// ---------------------------------------------------------------------------
// Attention — exact R2 version (j-split reverted: it cost BW and gained no TLP).
// ---------------------------------------------------------------------------
__global__ __launch_bounds__(256) void attn_kernel(
    const __hip_bfloat16* __restrict__ Q,
    const __hip_bfloat16* __restrict__ K,
    const __hip_bfloat16* __restrict__ V,
    const float* __restrict__ alpha, const float* __restrict__ phi,
    const float* __restrict__ temperature,
    __hip_bfloat16* __restrict__ AO)
{
    __shared__ __align__(16) char smem[18432 + 5120];
    __hip_bfloat16* VtBase = (__hip_bfloat16*)smem;
    __hip_bfloat16* PlBase = (__hip_bfloat16*)(smem + 18432);
    float* Ocomb = (float*)smem;                 // [2][16][68]
    float* Dl    = (float*)(smem + 2 * 16 * 68 * 4);

    const int tid = threadIdx.x;
    const int wv = tid >> 6, lane = tid & 63;
    const int col16 = lane & 15, quad = lane >> 4;
    const int g = wv & 1, half = wv >> 1;

    const int bh = blockIdx.y, b = bh >> 4, h = bh & 15;
    const int i0 = blockIdx.x * 32 + g * 16;
    const size_t base = ((size_t)b * SEQ) * DIM + (size_t)h * HD;

    const float tempv = fabsf(temperature[0]) + 0.1f;
    const float simscale = 1.0f / (8.0f * tempv);
    const float freqs[5] = {31.0f, 37.0f, 41.0f, 43.0f, 47.0f};

    // degree-7 poly of log2e*score(s); w = rcp(1+exp2(-poly(s)))  [R5-validated]
    float p[8] = {0.f, 0.f, 0.f, 0.f, 0.f, 0.f, 0.f, 0.f};
#pragma unroll
    for (int f = 0; f < 5; ++f) {
        const float a  = alpha[h * 5 + f] * 1.44269504089f;  // fold log2(e)
        const float ph = phi[h * 5 + f];
        const float sp = __sinf(ph), cp = __cosf(ph);
        const float c  = 6.28318530718f * simscale / freqs[f];
        const float c2 = c * c, c3 = c2 * c, c4 = c2 * c2;
        const float c5 = c4 * c, c6 = c4 * c2, c7 = c4 * c3;
        p[0] += a * sp;
        p[1] += a * cp * c;
        p[2] -= a * sp * c2 * 0.5f;
        p[3] -= a * cp * c3 * (1.0f / 6.0f);
        p[4] += a * sp * c4 * (1.0f / 24.0f);
        p[5] += a * cp * c5 * (1.0f / 120.0f);
        p[6] -= a * sp * c6 * (1.0f / 720.0f);
        p[7] -= a * cp * c7 * (1.0f / 5040.0f);
    }

    const __hip_bfloat16* qrow = Q + base + (size_t)(i0 + col16) * DIM + quad * 8;
    const bf16x8 qa0 = *(const bf16x8*)(qrow);
    const bf16x8 qa1 = *(const bf16x8*)(qrow + 32);

    const __hip_bfloat16* kbase = K + base + (size_t)col16 * DIM + quad * 8;

    const int tl = tid & 127;
    const int sc0 = (tl & 7) * 8;
    const int sx  = tl & 7;
    const int jj0 = (tl >> 3) * 2;
    __hip_bfloat16* VtH = VtBase + half * 64 * 72;
    __hip_bfloat16* rowp[8];
#pragma unroll
    for (int e = 0; e < 8; ++e) rowp[e] = VtH + (sc0 + (e ^ sx)) * 72;

    const __hip_bfloat16* vrd[4];
#pragma unroll
    for (int t = 0; t < 4; ++t)
        vrd[t] = VtH + swz(t * 16 + col16) * 72 + quad * 8;

    __hip_bfloat16* PlW = PlBase + wv * 16 * 40;
    const __hip_bfloat16* plr = PlW + swz(col16) * 40 + quad * 8;
    __hip_bfloat16* plw[4];
#pragma unroll
    for (int r = 0; r < 4; ++r) plw[r] = PlW + swz(quad * 4 + r) * 40;

    f32x4 o[4] = {};
    float denom[4] = {0.f, 0.f, 0.f, 0.f};

    bf16x8 vr[2][2];   // prefetched V regs
    bf16x8 kf[4][2];   // prefetched K frags

    {
        const int j0 = half * 512;
#pragma unroll
        for (int s = 0; s < 2; ++s) {
            const __hip_bfloat16* vp = V + base + (size_t)(j0 + jj0 + 32 * s) * DIM + sc0;
            vr[s][0] = *(const bf16x8*)(vp);
            vr[s][1] = *(const bf16x8*)(vp + DIM);
        }
#pragma unroll
        for (int u = 0; u < 4; ++u) {
            const __hip_bfloat16* kp = kbase + (size_t)(j0 + u * 16) * DIM;
            kf[u][0] = *(const bf16x8*)(kp);
            kf[u][1] = *(const bf16x8*)(kp + 32);
        }
    }

    for (int it = 0; it < 8; ++it) {
        __syncthreads();
#pragma unroll
        for (int s = 0; s < 2; ++s) {
#pragma unroll
            for (int e = 0; e < 8; ++e) {
                unsigned pk = ((unsigned)(unsigned short)vr[s][0][e]) |
                              (((unsigned)(unsigned short)vr[s][1][e]) << 16);
                *(unsigned*)(rowp[e] + jj0 + 32 * s) = pk;
            }
        }
        __syncthreads();

        const int j1 = half * 512 + (it + 1) * 64;
        if (it < 7) {
#pragma unroll
            for (int s = 0; s < 2; ++s) {
                const __hip_bfloat16* vp = V + base + (size_t)(j1 + jj0 + 32 * s) * DIM + sc0;
                vr[s][0] = *(const bf16x8*)(vp);
                vr[s][1] = *(const bf16x8*)(vp + DIM);
            }
        }

        f32x4 sa4[4];
#pragma unroll
        for (int u = 0; u < 4; ++u) {
            f32x4 zz = {};
            zz = MFMA16(qa0, kf[u][0], zz);
            zz = MFMA16(qa1, kf[u][1], zz);
            sa4[u] = zz;
        }

        if (it < 7) {
#pragma unroll
            for (int u = 0; u < 4; ++u) {
                const __hip_bfloat16* kp = kbase + (size_t)(j1 + u * 16) * DIM;
                kf[u][0] = *(const bf16x8*)(kp);
                kf[u][1] = *(const bf16x8*)(kp + 32);
            }
        }

#pragma unroll
        for (int sub = 0; sub < 2; ++sub) {
#pragma unroll
            for (int s2 = 0; s2 < 2; ++s2) {
                const int u = sub * 2 + s2;
#pragma unroll
                for (int r = 0; r < 4; ++r) {
                    const float sv = sa4[u][r];
                    float sc = fmaf(sv, p[7], p[6]);
                    sc = fmaf(sv, sc, p[5]);
                    sc = fmaf(sv, sc, p[4]);
                    sc = fmaf(sv, sc, p[3]);
                    sc = fmaf(sv, sc, p[2]);
                    sc = fmaf(sv, sc, p[1]);
                    sc = fmaf(sv, sc, p[0]);
                    const float w = FAST_RCP(1.0f + EXP2F(-sc));
                    denom[r] += w;
                    plw[r][s2 * 16 + col16] = __float2bfloat16(w);
                }
            }
            bf16x8 pa = *(const bf16x8*)plr;
#pragma unroll
            for (int t = 0; t < 4; ++t) {
                bf16x8 vb = *(const bf16x8*)(vrd[t] + 32 * sub);
                o[t] = MFMA16(pa, vb, o[t]);
            }
        }
    }

#pragma unroll
    for (int r = 0; r < 4; ++r) {
        float d = denom[r];
        d += __shfl_xor(d, 1);
        d += __shfl_xor(d, 2);
        d += __shfl_xor(d, 4);
        d += __shfl_xor(d, 8);
        denom[r] = d;
    }

    __syncthreads();
    if (half == 1) {
#pragma unroll
        for (int t = 0; t < 4; ++t)
#pragma unroll
            for (int r = 0; r < 4; ++r)
                Ocomb[(g * 16 + quad * 4 + r) * 68 + t * 16 + col16] = o[t][r];
        if (col16 == 0) {
#pragma unroll
            for (int r = 0; r < 4; ++r) Dl[g * 16 + quad * 4 + r] = denom[r];
        }
    }
    __syncthreads();
    if (half == 0) {
#pragma unroll
        for (int r = 0; r < 4; ++r)
            denom[r] = denom[r] + Dl[g * 16 + quad * 4 + r] + 1e-10f;
#pragma unroll
        for (int t = 0; t < 4; ++t) {
#pragma unroll
            for (int r = 0; r < 4; ++r) {
                const float val =
                    (o[t][r] + Ocomb[(g * 16 + quad * 4 + r) * 68 + t * 16 + col16]) / denom[r];
                const size_t row = (size_t)b * SEQ + i0 + quad * 4 + r;
                AO[row * DIM + h * HD + t * 16 + col16] = __float2bfloat16(val);
            }
        }
    }
}

// ---------------------------------------------------------------------------
// LayerNorm over last dim (1024), sums the two split-K partials of O-proj.
// ---------------------------------------------------------------------------
__global__ __launch_bounds__(256) void ln_kernel(
    const float* __restrict__ Yp0,
    const float* __restrict__ Yp1,
    const float* __restrict__ gamma,
    const float* __restrict__ beta,
    float* __restrict__ out)
{
    const int row = blockIdx.x;
    const float* y0 = Yp0 + (size_t)row * DIM;
    const float* y1 = Yp1 + (size_t)row * DIM;

    float v[4];
    float s = 0.f, s2 = 0.f;
#pragma unroll
    for (int e = 0; e < 4; ++e) {
        const int idx = threadIdx.x + e * 256;
        v[e] = y0[idx] + y1[idx];
        s += v[e];
        s2 += v[e] * v[e];
    }
#pragma unroll
    for (int off = 1; off < 64; off <<= 1) {
        s  += __shfl_xor(s, off);
        s2 += __shfl_xor(s2, off);
    }
    __shared__ float ps[4], ps2[4];
    const int wave = threadIdx.x >> 6;
    if ((threadIdx.x & 63) == 0) { ps[wave] = s; ps2[wave] = s2; }
    __syncthreads();
    s  = ps[0] + ps[1] + ps[2] + ps[3];
    s2 = ps2[0] + ps2[1] + ps2[2] + ps2[3];

    const float mu   = s * (1.0f / DIM);
    const float var  = s2 * (1.0f / DIM) - mu * mu;
    const float rstd = rsqrtf(var + 1e-5f);

#pragma unroll
    for (int e = 0; e < 4; ++e) {
        const int idx = threadIdx.x + e * 256;
        out[(size_t)row * DIM + idx] =
            (v[e] - mu) * rstd * gamma[idx] + beta[idx];
    }
}

// ---------------------------------------------------------------------------
extern "C" void kernel_launch(void* const* d_in, const int* in_sizes, int n_in,
                              void* d_out, int out_size, void* d_ws, size_t ws_size,
                              hipStream_t stream)
{
    const float* x     = (const float*)d_in[0];
    const float* Wq    = (const float*)d_in[1];
    const float* bq    = (const float*)d_in[2];
    const float* Wk    = (const float*)d_in[3];
    const float* bk    = (const float*)d_in[4];
    const float* Wv    = (const float*)d_in[5];
    const float* bv    = (const float*)d_in[6];
    const float* Wo    = (const float*)d_in[7];
    const float* bo    = (const float*)d_in[8];
    const float* alpha = (const float*)d_in[9];
    const float* phi   = (const float*)d_in[10];
    const float* temp  = (const float*)d_in[11];
    const float* gamma = (const float*)d_in[12];
    const float* beta  = (const float*)d_in[13];

    float* out = (float*)d_out;

    const int B = 2;
    const int M = B * SEQ;                 // 2048

    // ws layout (MB):
    //   [0,4)   xb    [4,6) Wqb   [6,8) Wkb   [8,10) Wvb   [10,12) Wob
    //   [12,16) Qb    [16,20) Kb  [20,24) Vb  [24,28) AO
    //   Yp0 (fp32 8MB) aliases [0,8)  — xb/Wqb/Wkb dead by O-proj
    //   Yp1 (fp32 8MB) aliases [12,20) — Qb/Kb dead by O-proj
    char* wsb = (char*)d_ws;
    __hip_bfloat16* xb  = (__hip_bfloat16*)(wsb + 0);
    __hip_bfloat16* Wqb = (__hip_bfloat16*)(wsb + (4u  << 20));
    __hip_bfloat16* Wkb = (__hip_bfloat16*)(wsb + (6u  << 20));
    __hip_bfloat16* Wvb = (__hip_bfloat16*)(wsb + (8u  << 20));
    __hip_bfloat16* Wob = (__hip_bfloat16*)(wsb + (10u << 20));
    __hip_bfloat16* Qb  = (__hip_bfloat16*)(wsb + (12u << 20));
    __hip_bfloat16* Kb  = (__hip_bfloat16*)(wsb + (16u << 20));
    __hip_bfloat16* Vb  = (__hip_bfloat16*)(wsb + (20u << 20));
    __hip_bfloat16* AO  = (__hip_bfloat16*)(wsb + (24u << 20));
    float*          Yp0 = (float*)(wsb + 0);
    float*          Yp1 = (float*)(wsb + (12u << 20));

    hipLaunchKernelGGL(cvt_all, dim3(2048, 5), dim3(256), 0, stream,
                       x, Wq, Wk, Wv, Wo, xb, Wqb, Wkb, Wvb, Wob);

    hipLaunchKernelGGL(gemm_qkv, dim3(M / 64, DIM / 128, 3), dim3(256), 0, stream,
                       xb, Wqb, Wkb, Wvb, bq, bk, bv, Qb, Kb, Vb, M, DIM, DIM);

    hipLaunchKernelGGL(attn_kernel, dim3(SEQ / 32, B * NH), dim3(256), 0, stream,
                       Qb, Kb, Vb, alpha, phi, temp, AO);

    hipLaunchKernelGGL(gemm_osplit, dim3(M / 64, DIM / 128, 2), dim3(256), 0, stream,
                       AO, Wob, bo, Yp0, Yp1, M, DIM, DIM);

    hipLaunchKernelGGL(ln_kernel, dim3(M), dim3(256), 0, stream,
                       Yp0, Yp1, gamma, beta, out);
}

// Round 7
// 169.636 us; speedup vs baseline: 1.0808x; 1.0093x over previous
//
#include <hip/hip_runtime.h>
#include <hip/hip_bf16.h>

typedef short bf16x8 __attribute__((ext_vector_type(8)));
typedef float f32x4 __attribute__((ext_vector_type(4)));

#define MFMA16(a, b, c) __builtin_amdgcn_mfma_f32_16x16x32_bf16(a, b, c, 0, 0, 0)

static constexpr int SEQ = 1024;
static constexpr int DIM = 1024;
static constexpr int NH = 16;
static constexpr int HD = 64;

#if __has_builtin(__builtin_amdgcn_rcpf)
#define FAST_RCP(x) __builtin_amdgcn_rcpf(x)
#else
#define FAST_RCP(x) (1.0f / (x))
#endif

#if __has_builtin(__builtin_amdgcn_exp2f)
#define EXP2F(x) __builtin_amdgcn_exp2f(x)
#else
#define EXP2F(x) exp2f(x)
#endif

__device__ __forceinline__ int swz(int r) { return r ^ (r >> 3); } // row-XOR bank swizzle

// async global->LDS, 16B per lane. lds ptr must be wave-uniform (HW adds lane*16).
__device__ __forceinline__ void gload16(const __hip_bfloat16* g, __hip_bfloat16* l)
{
    typedef const __attribute__((address_space(1))) unsigned GU;
    typedef __attribute__((address_space(3))) unsigned LU;
    __builtin_amdgcn_global_load_lds((GU*)g, (LU*)l, 16, 0, 0);
}

__device__ __forceinline__ unsigned pack2bf(float a, float b)
{
    union { __hip_bfloat16 h; unsigned short u; } ca, cb;
    ca.h = __float2bfloat16(a); cb.h = __float2bfloat16(b);
    return (unsigned)ca.u | ((unsigned)cb.u << 16);
}

// ---------------------------------------------------------------------------
// fused fp32->bf16 conversion for all 5 tensors (grid.y selects region)
// ---------------------------------------------------------------------------
__global__ __launch_bounds__(256) void cvt_all(
    const float* __restrict__ x,  const float* __restrict__ wq,
    const float* __restrict__ wk, const float* __restrict__ wv,
    const float* __restrict__ wo,
    __hip_bfloat16* __restrict__ xb,  __hip_bfloat16* __restrict__ wqb,
    __hip_bfloat16* __restrict__ wkb, __hip_bfloat16* __restrict__ wvb,
    __hip_bfloat16* __restrict__ wob)
{
    const int reg = blockIdx.y;
    const float* src; __hip_bfloat16* dst; int n;
    if      (reg == 0) { src = x;  dst = xb;  n = 2 * SEQ * DIM; }
    else if (reg == 1) { src = wq; dst = wqb; n = DIM * DIM; }
    else if (reg == 2) { src = wk; dst = wkb; n = DIM * DIM; }
    else if (reg == 3) { src = wv; dst = wvb; n = DIM * DIM; }
    else               { src = wo; dst = wob; n = DIM * DIM; }
    const int i = (blockIdx.x * 256 + threadIdx.x) * 4;
    if (i < n) {
        float4 v = *(const float4*)(src + i);
        __hip_bfloat16 t[4];
        t[0] = __float2bfloat16(v.x); t[1] = __float2bfloat16(v.y);
        t[2] = __float2bfloat16(v.z); t[3] = __float2bfloat16(v.w);
        *(ushort4*)(dst + i) = *(ushort4*)t;
    }
}

// ---------------------------------------------------------------------------
// GEMM 64x128 tile, BK=64, gload_lds + both-sides XOR swizzle (R6 winner).
// ---------------------------------------------------------------------------
__global__ __launch_bounds__(256) void gemm_qkv(
    const __hip_bfloat16* __restrict__ A,
    const __hip_bfloat16* __restrict__ W0, const __hip_bfloat16* __restrict__ W1,
    const __hip_bfloat16* __restrict__ W2,
    const float* __restrict__ b0, const float* __restrict__ b1,
    const float* __restrict__ b2,
    __hip_bfloat16* __restrict__ Y0, __hip_bfloat16* __restrict__ Y1,
    __hip_bfloat16* __restrict__ Y2,
    int M, int N, int K)
{
    __shared__ __align__(16) __hip_bfloat16 As[64 * 64];
    __shared__ __align__(16) __hip_bfloat16 Ws[128 * 64];

    const int z = blockIdx.z;
    const __hip_bfloat16* W = (z == 0) ? W0 : ((z == 1) ? W1 : W2);
    const float* bias = (z == 0) ? b0 : ((z == 1) ? b1 : b2);
    __hip_bfloat16* Y = (z == 0) ? Y0 : ((z == 1) ? Y1 : Y2);

    const int tid = threadIdx.x;
    const int wv = tid >> 6, lane = tid & 63;
    const int col16 = lane & 15, quad = lane >> 4;
    const int m0 = blockIdx.x * 64, n0 = blockIdx.y * 128;
    const int wr = wv >> 1, wc = wv & 1;

    const int scol = ((tid & 7) ^ ((tid >> 3) & 7)) * 8;
    const __hip_bfloat16* ga = A + (size_t)(m0 + (tid >> 3)) * K + scol;
    const __hip_bfloat16* gb = W + (size_t)(n0 + (tid >> 3)) * K + scol;
    __hip_bfloat16* lA = As + wv * 512;
    __hip_bfloat16* lB = Ws + wv * 512;

    const int c7 = col16 & 7;
    const int so0 = ((quad)     ^ c7) * 8;
    const int so1 = ((quad + 4) ^ c7) * 8;
    const __hip_bfloat16* ar = As + (wr * 32 + col16) * 64;
    const __hip_bfloat16* br = Ws + (wc * 64 + col16) * 64;

    f32x4 acc[8] = {};

    for (int k0 = 0; k0 < K; k0 += 64) {
        gload16(ga + k0,                  lA);
        gload16(ga + k0 + (size_t)32 * K, lA + 2048);
        gload16(gb + k0,                  lB);
        gload16(gb + k0 + (size_t)32 * K, lB + 2048);
        gload16(gb + k0 + (size_t)64 * K, lB + 4096);
        gload16(gb + k0 + (size_t)96 * K, lB + 6144);
        __syncthreads();
#pragma unroll
        for (int kh = 0; kh < 2; ++kh) {
            const int so = (kh == 0) ? so0 : so1;
            bf16x8 af[2], bfm[4];
#pragma unroll
            for (int mt = 0; mt < 2; ++mt) af[mt] = *(const bf16x8*)(ar + mt * 16 * 64 + so);
#pragma unroll
            for (int nt = 0; nt < 4; ++nt) bfm[nt] = *(const bf16x8*)(br + nt * 16 * 64 + so);
#pragma unroll
            for (int mt = 0; mt < 2; ++mt)
#pragma unroll
                for (int nt = 0; nt < 4; ++nt)
                    acc[mt * 4 + nt] = MFMA16(af[mt], bfm[nt], acc[mt * 4 + nt]);
        }
        __syncthreads();
    }

#pragma unroll
    for (int nt = 0; nt < 4; ++nt) {
        const int n = n0 + wc * 64 + nt * 16 + col16;
        const float bv = bias[n];
#pragma unroll
        for (int mt = 0; mt < 2; ++mt) {
#pragma unroll
            for (int r = 0; r < 4; ++r) {
                const int m = m0 + wr * 32 + mt * 16 + quad * 4 + r;
                Y[(size_t)m * N + n] = __float2bfloat16(acc[mt * 4 + nt][r] + bv);
            }
        }
    }
}

// ---------------------------------------------------------------------------
// O-proj split-K=2, same BK=64 swizzled structure (R6 winner).
// ---------------------------------------------------------------------------
__global__ __launch_bounds__(256) void gemm_osplit(
    const __hip_bfloat16* __restrict__ A,
    const __hip_bfloat16* __restrict__ W,
    const float* __restrict__ bias,
    float* __restrict__ Y0, float* __restrict__ Y1,
    int M, int N, int K)
{
    __shared__ __align__(16) __hip_bfloat16 As[64 * 64];
    __shared__ __align__(16) __hip_bfloat16 Ws[128 * 64];

    const int z = blockIdx.z;
    float* Y = (z == 0) ? Y0 : Y1;
    const int kb = z * 512;

    const int tid = threadIdx.x;
    const int wv = tid >> 6, lane = tid & 63;
    const int col16 = lane & 15, quad = lane >> 4;
    const int m0 = blockIdx.x * 64, n0 = blockIdx.y * 128;
    const int wr = wv >> 1, wc = wv & 1;

    const int scol = ((tid & 7) ^ ((tid >> 3) & 7)) * 8;
    const __hip_bfloat16* ga = A + (size_t)(m0 + (tid >> 3)) * K + scol + kb;
    const __hip_bfloat16* gb = W + (size_t)(n0 + (tid >> 3)) * K + scol + kb;
    __hip_bfloat16* lA = As + wv * 512;
    __hip_bfloat16* lB = Ws + wv * 512;

    const int c7 = col16 & 7;
    const int so0 = ((quad)     ^ c7) * 8;
    const int so1 = ((quad + 4) ^ c7) * 8;
    const __hip_bfloat16* ar = As + (wr * 32 + col16) * 64;
    const __hip_bfloat16* br = Ws + (wc * 64 + col16) * 64;

    f32x4 acc[8] = {};

    for (int k0 = 0; k0 < 512; k0 += 64) {
        gload16(ga + k0,                  lA);
        gload16(ga + k0 + (size_t)32 * K, lA + 2048);
        gload16(gb + k0,                  lB);
        gload16(gb + k0 + (size_t)32 * K, lB + 2048);
        gload16(gb + k0 + (size_t)64 * K, lB + 4096);
        gload16(gb + k0 + (size_t)96 * K, lB + 6144);
        __syncthreads();
#pragma unroll
        for (int kh = 0; kh < 2; ++kh) {
            const int so = (kh == 0) ? so0 : so1;
            bf16x8 af[2], bfm[4];
#pragma unroll
            for (int mt = 0; mt < 2; ++mt) af[mt] = *(const bf16x8*)(ar + mt * 16 * 64 + so);
#pragma unroll
            for (int nt = 0; nt < 4; ++nt) bfm[nt] = *(const bf16x8*)(br + nt * 16 * 64 + so);
#pragma unroll
            for (int mt = 0; mt < 2; ++mt)
#pragma unroll
                for (int nt = 0; nt < 4; ++nt)
                    acc[mt * 4 + nt] = MFMA16(af[mt], bfm[nt], acc[mt * 4 + nt]);
        }
        __syncthreads();
    }

#pragma unroll
    for (int nt = 0; nt < 4; ++nt) {
        const int n = n0 + wc * 64 + nt * 16 + col16;
        const float bv = (z == 0) ? bias[n] : 0.0f;
#pragma unroll
        for (int mt = 0; mt < 2; ++mt) {
#pragma unroll
            for (int r = 0; r < 4; ++r) {
                const int m = m0 + wr * 32 + mt * 16 + quad * 4 + r;
                Y[(size_t)m * N + n] = acc[mt * 4 + nt][r] + bv;
            }
        }
    }
}

// ---------------------------------------------------------------------------
// Attention — SWAPPED QK^T (T12): mfma(K,Q) puts i=col16 lane-local, so the
// P->PV A-fragment is built IN REGISTERS: u'=0 dwords stay in-lane, u'=1
// dwords cross via shfl_xor(32). Vt columns are permuted at pack time by
// pi(j) = (qs^2u')*8 + u'*4 + r (within each 32-j sub-block) so V's k-slot
// order matches. Pl LDS buffer deleted. Denom is one scalar/lane (i=col16),
// reduced via shfl_xor(16/32); both halves publish Dl[2][32] for epilogue.
// setprio(1) around MFMA clusters (T5, m191).
// ---------------------------------------------------------------------------
__global__ __launch_bounds__(256) void attn_kernel(
    const __hip_bfloat16* __restrict__ Q,
    const __hip_bfloat16* __restrict__ K,
    const __hip_bfloat16* __restrict__ V,
    const float* __restrict__ alpha, const float* __restrict__ phi,
    const float* __restrict__ temperature,
    __hip_bfloat16* __restrict__ AO)
{
    __shared__ __align__(16) char smem[18432 + 512];
    __hip_bfloat16* VtBase = (__hip_bfloat16*)smem;
    float* Ocomb = (float*)smem;                 // [2][16][68] (epilogue reuse)
    float* Dl    = (float*)(smem + 2 * 16 * 68 * 4);   // [2][32]

    const int tid = threadIdx.x;
    const int wv = tid >> 6, lane = tid & 63;
    const int col16 = lane & 15, quad = lane >> 4;
    const int g = wv & 1, half = wv >> 1;

    const int bh = blockIdx.y, b = bh >> 4, h = bh & 15;
    const int i0 = blockIdx.x * 32 + g * 16;
    const size_t base = ((size_t)b * SEQ) * DIM + (size_t)h * HD;

    const float tempv = fabsf(temperature[0]) + 0.1f;
    const float simscale = 1.0f / (8.0f * tempv);
    const float freqs[5] = {31.0f, 37.0f, 41.0f, 43.0f, 47.0f};

    // degree-7 poly of log2e*score(s); w = rcp(1+exp2(-poly(s)))  [R5-validated]
    float p[8] = {0.f, 0.f, 0.f, 0.f, 0.f, 0.f, 0.f, 0.f};
#pragma unroll
    for (int f = 0; f < 5; ++f) {
        const float a  = alpha[h * 5 + f] * 1.44269504089f;  // fold log2(e)
        const float ph = phi[h * 5 + f];
        const float sp = __sinf(ph), cp = __cosf(ph);
        const float c  = 6.28318530718f * simscale / freqs[f];
        const float c2 = c * c, c3 = c2 * c, c4 = c2 * c2;
        const float c5 = c4 * c, c6 = c4 * c2, c7 = c4 * c3;
        p[0] += a * sp;
        p[1] += a * cp * c;
        p[2] -= a * sp * c2 * 0.5f;
        p[3] -= a * cp * c3 * (1.0f / 6.0f);
        p[4] += a * sp * c4 * (1.0f / 24.0f);
        p[5] += a * cp * c5 * (1.0f / 120.0f);
        p[6] -= a * sp * c6 * (1.0f / 720.0f);
        p[7] -= a * cp * c7 * (1.0f / 5040.0f);
    }

    const __hip_bfloat16* qrow = Q + base + (size_t)(i0 + col16) * DIM + quad * 8;
    const bf16x8 qa0 = *(const bf16x8*)(qrow);
    const bf16x8 qa1 = *(const bf16x8*)(qrow + 32);

    const __hip_bfloat16* kbase = K + base + (size_t)col16 * DIM + quad * 8;

    // Vt staging: 128 threads per half; thread: 8 d-rows x 1 j-pair x 2 blocks
    const int tl = tid & 127;
    const int sc0 = (tl & 7) * 8;
    const int sx  = tl & 7;
    const int jj0 = (tl >> 3) * 2;
    // column permutation pi(j) within 32-j sub-block (j-pair keeps r,r+1 adjacent)
    const int pu = (jj0 >> 4) & 1, pqs = (jj0 >> 2) & 3, pr = jj0 & 3;
    const int col0 = ((pqs ^ (pu << 1)) << 3) + (pu << 2) + pr;   // pi(jj0), jj0<32
    __hip_bfloat16* VtH = VtBase + half * 64 * 72;
    __hip_bfloat16* rowp[8];
#pragma unroll
    for (int e = 0; e < 8; ++e) rowp[e] = VtH + (sc0 + (e ^ sx)) * 72;

    const __hip_bfloat16* vrd[4];
#pragma unroll
    for (int t = 0; t < 4; ++t)
        vrd[t] = VtH + swz(t * 16 + col16) * 72 + quad * 8;

    f32x4 o[4] = {};
    float denomL = 0.f;

    bf16x8 vr[2][2];   // prefetched V regs
    bf16x8 kf[4][2];   // prefetched K frags

    {
        const int j0 = half * 512;
#pragma unroll
        for (int s = 0; s < 2; ++s) {
            const __hip_bfloat16* vp = V + base + (size_t)(j0 + jj0 + 32 * s) * DIM + sc0;
            vr[s][0] = *(const bf16x8*)(vp);
            vr[s][1] = *(const bf16x8*)(vp + DIM);
        }
#pragma unroll
        for (int u = 0; u < 4; ++u) {
            const __hip_bfloat16* kp = kbase + (size_t)(j0 + u * 16) * DIM;
            kf[u][0] = *(const bf16x8*)(kp);
            kf[u][1] = *(const bf16x8*)(kp + 32);
        }
    }

    for (int it = 0; it < 8; ++it) {
        __syncthreads();
        // pack prefetched V into permuted-column transposed LDS tile
#pragma unroll
        for (int s = 0; s < 2; ++s) {
#pragma unroll
            for (int e = 0; e < 8; ++e) {
                unsigned pk = ((unsigned)(unsigned short)vr[s][0][e]) |
                              (((unsigned)(unsigned short)vr[s][1][e]) << 16);
                *(unsigned*)(rowp[e] + col0 + 32 * s) = pk;
            }
        }
        __syncthreads();

        const int j1 = half * 512 + (it + 1) * 64;
        if (it < 7) {
#pragma unroll
            for (int s = 0; s < 2; ++s) {
                const __hip_bfloat16* vp = V + base + (size_t)(j1 + jj0 + 32 * s) * DIM + sc0;
                vr[s][0] = *(const bf16x8*)(vp);
                vr[s][1] = *(const bf16x8*)(vp + DIM);
            }
        }

        // swapped QK^T: lane holds S[j = u*16 + quad*4 + r][i = col16]
        f32x4 sa4[4];
        __builtin_amdgcn_s_setprio(1);
#pragma unroll
        for (int u = 0; u < 4; ++u) {
            f32x4 zz = {};
            zz = MFMA16(kf[u][0], qa0, zz);
            zz = MFMA16(kf[u][1], qa1, zz);
            sa4[u] = zz;
        }
        __builtin_amdgcn_s_setprio(0);

        if (it < 7) {
#pragma unroll
            for (int u = 0; u < 4; ++u) {
                const __hip_bfloat16* kp = kbase + (size_t)(j1 + u * 16) * DIM;
                kf[u][0] = *(const bf16x8*)(kp);
                kf[u][1] = *(const bf16x8*)(kp + 32);
            }
        }

#pragma unroll
        for (int sub = 0; sub < 2; ++sub) {
            float w[2][4];
#pragma unroll
            for (int s2 = 0; s2 < 2; ++s2) {
                const int u = sub * 2 + s2;
#pragma unroll
                for (int r = 0; r < 4; ++r) {
                    const float sv = sa4[u][r];
                    float sc = fmaf(sv, p[7], p[6]);
                    sc = fmaf(sv, sc, p[5]);
                    sc = fmaf(sv, sc, p[4]);
                    sc = fmaf(sv, sc, p[3]);
                    sc = fmaf(sv, sc, p[2]);
                    sc = fmaf(sv, sc, p[1]);
                    sc = fmaf(sv, sc, p[0]);
                    const float ww = FAST_RCP(1.0f + EXP2F(-sc));
                    denomL += ww;
                    w[s2][r] = ww;
                }
            }
            // in-register P fragment: u'=0 stays, u'=1 crosses lane^32
            const unsigned pk00 = pack2bf(w[0][0], w[0][1]);
            const unsigned pk01 = pack2bf(w[0][2], w[0][3]);
            const unsigned pk10 = pack2bf(w[1][0], w[1][1]);
            const unsigned pk11 = pack2bf(w[1][2], w[1][3]);
            const unsigned sw0 = (unsigned)__shfl_xor((int)pk10, 32);
            const unsigned sw1 = (unsigned)__shfl_xor((int)pk11, 32);
            union { unsigned d[4]; bf16x8 v; } pu8;
            pu8.d[0] = pk00; pu8.d[1] = pk01; pu8.d[2] = sw0; pu8.d[3] = sw1;
            const bf16x8 pa = pu8.v;

            __builtin_amdgcn_s_setprio(1);
#pragma unroll
            for (int t = 0; t < 4; ++t) {
                bf16x8 vb = *(const bf16x8*)(vrd[t] + 32 * sub);
                o[t] = MFMA16(pa, vb, o[t]);
            }
            __builtin_amdgcn_s_setprio(0);
        }
    }

    // denom: lane holds partial for i=col16 over its js; reduce across quads
    denomL += __shfl_xor(denomL, 16);
    denomL += __shfl_xor(denomL, 32);

    __syncthreads();
    if (quad == 0) Dl[half * 32 + g * 16 + col16] = denomL;
    if (half == 1) {
#pragma unroll
        for (int t = 0; t < 4; ++t)
#pragma unroll
            for (int r = 0; r < 4; ++r)
                Ocomb[(g * 16 + quad * 4 + r) * 68 + t * 16 + col16] = o[t][r];
    }
    __syncthreads();
    if (half == 0) {
        float dn[4];
#pragma unroll
        for (int r = 0; r < 4; ++r)
            dn[r] = Dl[g * 16 + quad * 4 + r] + Dl[32 + g * 16 + quad * 4 + r] + 1e-10f;
#pragma unroll
        for (int t = 0; t < 4; ++t) {
#pragma unroll
            for (int r = 0; r < 4; ++r) {
                const float val =
                    (o[t][r] + Ocomb[(g * 16 + quad * 4 + r) * 68 + t * 16 + col16]) / dn[r];
                const size_t row = (size_t)b * SEQ + i0 + quad * 4 + r;
                AO[row * DIM + h * HD + t * 16 + col16] = __float2bfloat16(val);
            }
        }
    }
}

// ---------------------------------------------------------------------------
// LayerNorm over last dim (1024), sums the two split-K partials of O-proj.
// ---------------------------------------------------------------------------
__global__ __launch_bounds__(256) void ln_kernel(
    const float* __restrict__ Yp0,
    const float* __restrict__ Yp1,
    const float* __restrict__ gamma,
    const float* __restrict__ beta,
    float* __restrict__ out)
{
    const int row = blockIdx.x;
    const float* y0 = Yp0 + (size_t)row * DIM;
    const float* y1 = Yp1 + (size_t)row * DIM;

    float v[4];
    float s = 0.f, s2 = 0.f;
#pragma unroll
    for (int e = 0; e < 4; ++e) {
        const int idx = threadIdx.x + e * 256;
        v[e] = y0[idx] + y1[idx];
        s += v[e];
        s2 += v[e] * v[e];
    }
#pragma unroll
    for (int off = 1; off < 64; off <<= 1) {
        s  += __shfl_xor(s, off);
        s2 += __shfl_xor(s2, off);
    }
    __shared__ float ps[4], ps2[4];
    const int wave = threadIdx.x >> 6;
    if ((threadIdx.x & 63) == 0) { ps[wave] = s; ps2[wave] = s2; }
    __syncthreads();
    s  = ps[0] + ps[1] + ps[2] + ps[3];
    s2 = ps2[0] + ps2[1] + ps2[2] + ps2[3];

    const float mu   = s * (1.0f / DIM);
    const float var  = s2 * (1.0f / DIM) - mu * mu;
    const float rstd = rsqrtf(var + 1e-5f);

#pragma unroll
    for (int e = 0; e < 4; ++e) {
        const int idx = threadIdx.x + e * 256;
        out[(size_t)row * DIM + idx] =
            (v[e] - mu) * rstd * gamma[idx] + beta[idx];
    }
}

// ---------------------------------------------------------------------------
extern "C" void kernel_launch(void* const* d_in, const int* in_sizes, int n_in,
                              void* d_out, int out_size, void* d_ws, size_t ws_size,
                              hipStream_t stream)
{
    const float* x     = (const float*)d_in[0];
    const float* Wq    = (const float*)d_in[1];
    const float* bq    = (const float*)d_in[2];
    const float* Wk    = (const float*)d_in[3];
    const float* bk    = (const float*)d_in[4];
    const float* Wv    = (const float*)d_in[5];
    const float* bv    = (const float*)d_in[6];
    const float* Wo    = (const float*)d_in[7];
    const float* bo    = (const float*)d_in[8];
    const float* alpha = (const float*)d_in[9];
    const float* phi   = (const float*)d_in[10];
    const float* temp  = (const float*)d_in[11];
    const float* gamma = (const float*)d_in[12];
    const float* beta  = (const float*)d_in[13];

    float* out = (float*)d_out;

    const int B = 2;
    const int M = B * SEQ;                 // 2048

    // ws layout (MB):
    //   [0,4)   xb    [4,6) Wqb   [6,8) Wkb   [8,10) Wvb   [10,12) Wob
    //   [12,16) Qb    [16,20) Kb  [20,24) Vb  [24,28) AO
    //   Yp0 (fp32 8MB) aliases [0,8)  — xb/Wqb/Wkb dead by O-proj
    //   Yp1 (fp32 8MB) aliases [12,20) — Qb/Kb dead by O-proj
    char* wsb = (char*)d_ws;
    __hip_bfloat16* xb  = (__hip_bfloat16*)(wsb + 0);
    __hip_bfloat16* Wqb = (__hip_bfloat16*)(wsb + (4u  << 20));
    __hip_bfloat16* Wkb = (__hip_bfloat16*)(wsb + (6u  << 20));
    __hip_bfloat16* Wvb = (__hip_bfloat16*)(wsb + (8u  << 20));
    __hip_bfloat16* Wob = (__hip_bfloat16*)(wsb + (10u << 20));
    __hip_bfloat16* Qb  = (__hip_bfloat16*)(wsb + (12u << 20));
    __hip_bfloat16* Kb  = (__hip_bfloat16*)(wsb + (16u << 20));
    __hip_bfloat16* Vb  = (__hip_bfloat16*)(wsb + (20u << 20));
    __hip_bfloat16* AO  = (__hip_bfloat16*)(wsb + (24u << 20));
    float*          Yp0 = (float*)(wsb + 0);
    float*          Yp1 = (float*)(wsb + (12u << 20));

    hipLaunchKernelGGL(cvt_all, dim3(2048, 5), dim3(256), 0, stream,
                       x, Wq, Wk, Wv, Wo, xb, Wqb, Wkb, Wvb, Wob);

    hipLaunchKernelGGL(gemm_qkv, dim3(M / 64, DIM / 128, 3), dim3(256), 0, stream,
                       xb, Wqb, Wkb, Wvb, bq, bk, bv, Qb, Kb, Vb, M, DIM, DIM);

    hipLaunchKernelGGL(attn_kernel, dim3(SEQ / 32, B * NH), dim3(256), 0, stream,
                       Qb, Kb, Vb, alpha, phi, temp, AO);

    hipLaunchKernelGGL(gemm_osplit, dim3(M / 64, DIM / 128, 2), dim3(256), 0, stream,
                       AO, Wob, bo, Yp0, Yp1, M, DIM, DIM);

    hipLaunchKernelGGL(ln_kernel, dim3(M), dim3(256), 0, stream,
                       Yp0, Yp1, gamma, beta, out);
}